// Round 5
// baseline (87.787 us; speedup 1.0000x reference)
//
#include <hip/hip_runtime.h>
#include <math.h>

#define DIMC 768
#define BATCH 16
#define HWSZ 1024
#define NT 32
#define SCH 16          // channel splits
#define CHPB 48         // channels per block
#define CPM 4           // channels per macro-iter
#define NMAC 12         // macro-iters (48/4)

// out layout: result [16*32*768] | p [16*32*768] | mask [16*32*1024]
#define OUT_P_OFF    393216
#define OUT_MASK_OFF 786432

// ws layout (floats): partials [16][16][32][1024] = 8388608 | wt [768*32]
#define WS_WT_OFF 8388608

// ---------------- K0: transpose pww[t][c] -> wt[c][t] ----------------------
__global__ __launch_bounds__(256) void k0_transpose(
    const float* __restrict__ pww, float* __restrict__ wt)
{
    int i = blockIdx.x * 256 + threadIdx.x;   // < 768*32
    wt[i] = pww[(i & 31) * DIMC + (i >> 5)];
}

// ---------------- KF: fused BN + dw3x3 + hardswish + pointwise partials ----
// grid (pos-chunk=4, ch-chunk=16, b=16), 256 threads; lane owns one position.
// 4 channels per barrier-iteration; double-buffered 4x(10x34) LDS tiles.

#define ACC4(G) float a##G##0 = 0.f, a##G##1 = 0.f, a##G##2 = 0.f, a##G##3 = 0.f;
#define PW4(G, W) { a##G##0 = fmaf(hs, W.x, a##G##0); a##G##1 = fmaf(hs, W.y, a##G##1); \
                    a##G##2 = fmaf(hs, W.z, a##G##2); a##G##3 = fmaf(hs, W.w, a##G##3); }
#define STG4(G) { po[(size_t)(4*G+0) << 10] = a##G##0; po[(size_t)(4*G+1) << 10] = a##G##1; \
                  po[(size_t)(4*G+2) << 10] = a##G##2; po[(size_t)(4*G+3) << 10] = a##G##3; }

// depthwise 3x3 + hardswish + 32-token pointwise for channel (cm+Q)
#define CONV_PW(Q) { \
    const int c = cm + Q; \
    const float* wd = dww + c * 9; \
    float r = dwb[c]; \
    const float* S = Sc + (Q) * 340 + base; \
    r = fmaf(wd[0], S[0],  r); \
    r = fmaf(wd[1], S[1],  r); \
    r = fmaf(wd[2], S[2],  r); \
    r = fmaf(wd[3], S[34], r); \
    r = fmaf(wd[4], S[35], r); \
    r = fmaf(wd[5], S[36], r); \
    r = fmaf(wd[6], S[68], r); \
    r = fmaf(wd[7], S[69], r); \
    r = fmaf(wd[8], S[70], r); \
    float clp = fminf(fmaxf(r + 3.0f, 0.0f), 6.0f); \
    float hs  = r * clp * (1.0f / 6.0f); \
    const float4* wv = (const float4*)(wt + c * NT); \
    float4 wA = wv[0], wB = wv[1], wC = wv[2], wD = wv[3], \
           wE = wv[4], wF = wv[5], wG = wv[6], wH = wv[7]; \
    PW4(0, wA) PW4(1, wB) PW4(2, wC) PW4(3, wD) \
    PW4(4, wE) PW4(5, wF) PW4(6, wG) PW4(7, wH) }

__device__ __forceinline__ float sel4(int cu, float v0, float v1, float v2, float v3)
{
    float a = (cu & 1) ? v1 : v0;
    float b = (cu & 1) ? v3 : v2;
    return (cu & 2) ? b : a;
}

__global__ __launch_bounds__(256) void kf_fused(
    const float* __restrict__ x,
    const float* __restrict__ bnw, const float* __restrict__ bnb,
    const float* __restrict__ bnm, const float* __restrict__ bnv,
    const float* __restrict__ dww, const float* __restrict__ dwb,
    const float* __restrict__ wt,
    float* __restrict__ partials)
{
    const int b   = blockIdx.z;
    const int scc = blockIdx.y;
    const int cb0 = scc * CHPB;
    const int r0  = blockIdx.x * 8;           // first output row
    const int tid = threadIdx.x;
    const int rl  = tid >> 5;                 // local row 0..7
    const int col = tid & 31;

    __shared__ float st[2][CPM * 340];        // 10.9 KB, zero-padded halos

    // zero both buffers once; invalid (halo) slots are never rewritten
    for (int i = tid; i < 2 * CPM * 340; i += 256) ((float*)st)[i] = 0.0f;

    // slot geometry: flat index tid+256u over [4][10][34]; iteration-invariant
    int  soff[6]; bool svalid[6]; int scu[6];
#pragma unroll
    for (int u = 0; u < 6; ++u) {
        int idx = tid + 256 * u;
        int cu  = idx / 340;
        int rem = idx - cu * 340;
        int sr  = rem / 34, sc = rem - sr * 34;
        int rr  = r0 - 1 + sr, cc = sc - 1;
        svalid[u] = (idx < CPM * 340) && rr >= 0 && rr < 32 && cc >= 0 && cc < 32;
        scu[u]  = cu;
        soff[u] = cu * HWSZ + rr * 32 + cc;
    }

    const float* xb = x + (size_t)(b * DIMC) * HWSZ;

    // prologue: stage macro 0 into buf 0 (same-thread indices as zero loop)
    {
        const int cm = cb0;
        float g[6];
#pragma unroll
        for (int u = 0; u < 6; ++u)
            g[u] = svalid[u] ? xb[(size_t)cm * HWSZ + soff[u]] : 0.0f;
        float s0 = bnw[cm+0] * rsqrtf(bnv[cm+0] + 1e-5f), h0 = bnb[cm+0] - bnm[cm+0] * s0;
        float s1 = bnw[cm+1] * rsqrtf(bnv[cm+1] + 1e-5f), h1 = bnb[cm+1] - bnm[cm+1] * s1;
        float s2 = bnw[cm+2] * rsqrtf(bnv[cm+2] + 1e-5f), h2 = bnb[cm+2] - bnm[cm+2] * s2;
        float s3 = bnw[cm+3] * rsqrtf(bnv[cm+3] + 1e-5f), h3 = bnb[cm+3] - bnm[cm+3] * s3;
        float* Sn = &st[0][0];
#pragma unroll
        for (int u = 0; u < 6; ++u) {
            float scl = sel4(scu[u], s0, s1, s2, s3);
            float shf = sel4(scu[u], h0, h1, h2, h3);
            if (svalid[u]) Sn[tid + 256 * u] = fmaf(g[u], scl, shf);
        }
    }
    __syncthreads();

    ACC4(0) ACC4(1) ACC4(2) ACC4(3) ACC4(4) ACC4(5) ACC4(6) ACC4(7)

    const int base = rl * 34 + col;

    for (int m = 0; m < NMAC; ++m) {
        const int cm = cb0 + m * CPM;
        const float* Sc = &st[m & 1][0];

        // T14 split: issue next macro-tile's loads before compute
        float g[6];
        if (m < NMAC - 1) {
            const int cn = cm + CPM;
#pragma unroll
            for (int u = 0; u < 6; ++u)
                g[u] = svalid[u] ? xb[(size_t)cn * HWSZ + soff[u]] : 0.0f;
        }

        CONV_PW(0) CONV_PW(1) CONV_PW(2) CONV_PW(3)

        // late BN + LDS write (loads were in flight across the compute)
        if (m < NMAC - 1) {
            const int cn = cm + CPM;
            float s0 = bnw[cn+0] * rsqrtf(bnv[cn+0] + 1e-5f), h0 = bnb[cn+0] - bnm[cn+0] * s0;
            float s1 = bnw[cn+1] * rsqrtf(bnv[cn+1] + 1e-5f), h1 = bnb[cn+1] - bnm[cn+1] * s1;
            float s2 = bnw[cn+2] * rsqrtf(bnv[cn+2] + 1e-5f), h2 = bnb[cn+2] - bnm[cn+2] * s2;
            float s3 = bnw[cn+3] * rsqrtf(bnv[cn+3] + 1e-5f), h3 = bnb[cn+3] - bnm[cn+3] * s3;
            float* Sn = &st[(m & 1) ^ 1][0];
#pragma unroll
            for (int u = 0; u < 6; ++u) {
                float scl = sel4(scu[u], s0, s1, s2, s3);
                float shf = sel4(scu[u], h0, h1, h2, h3);
                if (svalid[u]) Sn[tid + 256 * u] = fmaf(g[u], scl, shf);
            }
        }
        __syncthreads();
    }

    float* po = partials + ((size_t)(scc * BATCH + b) * NT) * HWSZ
              + blockIdx.x * 256 + tid;
    STG4(0) STG4(1) STG4(2) STG4(3) STG4(4) STG4(5) STG4(6) STG4(7)
}

// ---------------- K3: sum partials -> argmax mask -> gather-sum ------------
__global__ __launch_bounds__(256) void k3_mask_gather(
    const float* __restrict__ partials,
    const float* __restrict__ x, const float* __restrict__ posin,
    const float* __restrict__ bnw, const float* __restrict__ bnb,
    const float* __restrict__ bnm, const float* __restrict__ bnv,
    float* __restrict__ out)
{
    int bt = blockIdx.x;           // b*32 + t
    int b  = bt >> 5;
    int t  = bt & 31;
    int tid = threadIdx.x;

    // sum 16 partial slabs, float4 per lane (positions 4*tid..4*tid+3)
    const float4* pp4 = (const float4*)(partials + ((size_t)(b * NT) + t) * HWSZ) + tid;
    float4 acc = make_float4(0.f, 0.f, 0.f, 0.f);
#pragma unroll
    for (int s = 0; s < SCH; ++s) {
        float4 u = pp4[(size_t)s * (BATCH * NT * HWSZ / 4)];
        acc.x += u.x; acc.y += u.y; acc.z += u.z; acc.w += u.w;
    }

    float m = fmaxf(fmaxf(acc.x, acc.y), fmaxf(acc.z, acc.w));
#pragma unroll
    for (int off = 32; off; off >>= 1)
        m = fmaxf(m, __shfl_xor(m, off));
    __shared__ float wm[4];
    if ((tid & 63) == 0) wm[tid >> 6] = m;
    __syncthreads();
    m = fmaxf(fmaxf(wm[0], wm[1]), fmaxf(wm[2], wm[3]));

    __shared__ int nmatch;
    __shared__ int matchpos[16];
    if (tid == 0) nmatch = 0;
    __syncthreads();

    float* maskp = out + OUT_MASK_OFF + (size_t)bt * HWSZ;
    float4 mask4;
    const float* av = &acc.x;
    float* mv = &mask4.x;
#pragma unroll
    for (int j = 0; j < 4; ++j) {
        int hit = (av[j] == m);
        mv[j] = hit ? 1.0f : 0.0f;
        if (hit) {
            int k = atomicAdd(&nmatch, 1);
            if (k < 16) matchpos[k] = 4 * tid + j;
        }
    }
    ((float4*)maskp)[tid] = mask4;
    __syncthreads();
    int nm = nmatch < 16 ? nmatch : 16;

    const float* xb = x + (size_t)b * DIMC * HWSZ;
    const float* pb = posin + (size_t)b * DIMC * HWSZ;
    for (int c = tid; c < DIMC; c += 256) {
        float scale = bnw[c] * rsqrtf(bnv[c] + 1e-5f);
        float shift = bnb[c] - bnm[c] * scale;
        float rf = 0.0f, rp = 0.0f;
        for (int k = 0; k < nm; ++k) {
            int pos = matchpos[k];
            rf += xb[(size_t)c * HWSZ + pos] * scale + shift;
            rp += pb[(size_t)c * HWSZ + pos];
        }
        out[(size_t)bt * DIMC + c] = rf;
        out[OUT_P_OFF + (size_t)bt * DIMC + c] = rp;
    }
}

extern "C" void kernel_launch(void* const* d_in, const int* in_sizes, int n_in,
                              void* d_out, int out_size, void* d_ws, size_t ws_size,
                              hipStream_t stream)
{
    const float* x    = (const float*)d_in[0];
    const float* pos  = (const float*)d_in[1];
    const float* bnw  = (const float*)d_in[2];
    const float* bnb  = (const float*)d_in[3];
    const float* bnm  = (const float*)d_in[4];
    const float* bnv  = (const float*)d_in[5];
    const float* dww  = (const float*)d_in[6];
    const float* dwb  = (const float*)d_in[7];
    const float* pww  = (const float*)d_in[8];
    // d_in[9] (pw_bias) unused: constant per (b,t) row -> outputs invariant.
    float* out = (float*)d_out;

    float* partials = (float*)d_ws;
    float* wt       = (float*)d_ws + WS_WT_OFF;

    k0_transpose<<<96, 256, 0, stream>>>(pww, wt);
    kf_fused<<<dim3(4, SCH, BATCH), 256, 0, stream>>>(x, bnw, bnb, bnm, bnv,
                                                      dww, dwb, wt, partials);
    k3_mask_gather<<<BATCH * NT, 256, 0, stream>>>(partials, x, pos,
                                                   bnw, bnb, bnm, bnv, out);
}